// Round 3
// baseline (1441.674 us; speedup 1.0000x reference)
//
#include <hip/hip_runtime.h>

typedef __bf16 bf16;
typedef __bf16 bf16x8 __attribute__((ext_vector_type(8)));
typedef __bf16 bf16x4 __attribute__((ext_vector_type(4)));
typedef float  f32x4  __attribute__((ext_vector_type(4)));

#define BATCH 16
#define SEQ   1024
#define DIM   512
#define HEADS 8
#define BN    (BATCH*SEQ)
#define QK_SCALE 0.04419417382415922f  /* 1/sqrt(512) */

// ---------------------------------------------------------------- utilities

__device__ __forceinline__ void load16_lds(const void* g, void* l) {
  // async global->LDS, 16B per lane; LDS dest = wave-uniform base + lane*16
  __builtin_amdgcn_global_load_lds((__attribute__((address_space(1))) void*)g,
                                   (__attribute__((address_space(3))) void*)l,
                                   16, 0, 0);
}

// ---------------------------------------------------------------- GEMM core
// C_tile(128x128) += A_tile(128xK) * B_tile(128xK)^T, bf16 in, fp32 acc.
// 2-phase prefetch double-buffer; single __syncthreads per K-step.
// RS: also accumulate row-sums of A via ones-vector MFMA.
template<bool RS>
__device__ __forceinline__ void gemm_tile(const bf16* __restrict__ Atile, int lda,
                                          const bf16* __restrict__ Btile, int ldb,
                                          int K, f32x4 acc[4][4], f32x4 rs[4])
{
  __shared__ bf16 As[2][128*32];
  __shared__ bf16 Bs[2][128*32];
  const int tid  = threadIdx.x;
  const int wave = tid >> 6;
  const int lane = tid & 63;
  const int wm = wave >> 1, wn = wave & 1;
  const int srow = lane >> 2;          // staging: row within 16-row chunk
  const int scol = (lane & 3) * 8;     // staging: k-offset (8 bf16 = 16B)
  const int frow = lane & 15;          // fragment row/col within 16-tile
  const int kq   = (lane >> 4) * 8;    // fragment k-offset

  bf16x8 ones;
#pragma unroll
  for (int j = 0; j < 8; ++j) ones[j] = (bf16)1.0f;

  __syncthreads();                     // protect LDS reuse (callers loop)
#pragma unroll
  for (int i = 0; i < 2; ++i) {        // prologue: stage tile 0 -> buf 0
    const int c = wave * 2 + i;
    load16_lds(Atile + (size_t)(c*16 + srow) * lda + scol, &As[0][c*512]);
    load16_lds(Btile + (size_t)(c*16 + srow) * ldb + scol, &Bs[0][c*512]);
  }
  __syncthreads();                     // vmcnt(0) drained: buf 0 ready

  int cur = 0;
  for (int kt = 0; kt < K; kt += 32) {
    const int nxt = kt + 32;
    if (nxt < K) {                     // prefetch next tile into buf cur^1
#pragma unroll
      for (int i = 0; i < 2; ++i) {
        const int c = wave * 2 + i;
        load16_lds(Atile + (size_t)(c*16 + srow) * lda + nxt + scol, &As[cur^1][c*512]);
        load16_lds(Btile + (size_t)(c*16 + srow) * ldb + nxt + scol, &Bs[cur^1][c*512]);
      }
    }
    bf16x8 af[4], bfr[4];
#pragma unroll
    for (int mi = 0; mi < 4; ++mi)
      af[mi] = *(const bf16x8*)(&As[cur][(wm*64 + mi*16 + frow)*32 + kq]);
#pragma unroll
    for (int ni = 0; ni < 4; ++ni)
      bfr[ni] = *(const bf16x8*)(&Bs[cur][(wn*64 + ni*16 + frow)*32 + kq]);
#pragma unroll
    for (int mi = 0; mi < 4; ++mi) {
#pragma unroll
      for (int ni = 0; ni < 4; ++ni)
        acc[mi][ni] = __builtin_amdgcn_mfma_f32_16x16x32_bf16(af[mi], bfr[ni],
                                                              acc[mi][ni], 0, 0, 0);
      if (RS)
        rs[mi] = __builtin_amdgcn_mfma_f32_16x16x32_bf16(af[mi], ones, rs[mi], 0, 0, 0);
    }
    __syncthreads();                   // drains prefetch vmcnt; all reads done
    cur ^= 1;
  }
}

// C/D fragment mapping (m89-verified): col = lane&15, row = (lane>>4)*4 + r.

// ----------------------------------------------------- weight-prep kernels

// fp32 -> bf16 cast, 8 elems/thread
__global__ __launch_bounds__(256)
void k_cast(const float* __restrict__ in, bf16* __restrict__ out, int n8)
{
  const int i = blockIdx.x*256 + threadIdx.x;
  if (i >= n8) return;
  const float4* p = (const float4*)in + (size_t)i*2;
  const float4 a = p[0], b = p[1];
  bf16x8 o;
  o[0]=(bf16)a.x; o[1]=(bf16)a.y; o[2]=(bf16)a.z; o[3]=(bf16)a.w;
  o[4]=(bf16)b.x; o[5]=(bf16)b.y; o[6]=(bf16)b.z; o[7]=(bf16)b.w;
  *((bf16x8*)out + i) = o;
}

// T[h][d][e] = W[h][e][d], split into hi/lo bf16 (lo = v - (float)hi)
__global__ __launch_bounds__(256)
void k_trans_hilo(const float* __restrict__ W, bf16* __restrict__ Thi,
                  bf16* __restrict__ Tlo)
{
  const int idx = blockIdx.x*256 + threadIdx.x;   // h*2^18 + d*2^9 + e
  const int e = idx & 511, d = (idx >> 9) & 511, h = idx >> 18;
  const float v = W[((size_t)(h*DIM + e))*DIM + d];
  const bf16 hi = (bf16)v;
  Thi[idx] = hi;
  Tlo[idx] = (bf16)(v - (float)hi);
}

// Wor[h][o][e] = Wo[o][e*8+h], hi/lo split
__global__ __launch_bounds__(256)
void k_wor_hilo(const float* __restrict__ Wo, bf16* __restrict__ Whi,
                bf16* __restrict__ Wlo)
{
  const int idx = blockIdx.x*256 + threadIdx.x;   // h*2^18 + o*2^9 + e
  const int e = idx & 511, o = (idx >> 9) & 511, h = idx >> 18;
  const float v = Wo[((size_t)o << 12) + (e << 3) + h];
  const bf16 hi = (bf16)v;
  Whi[idx] = hi;
  Wlo[idx] = (bf16)(v - (float)hi);
}

// C[z][m][n] = sum_k A[z][m][k]*B[z][n][k] with hi/lo split (3 cross terms),
// bf16 output.  Used for MT = WkT x WqT  and  G = Wor x WvT.
__global__ __launch_bounds__(256)
void k_gemm3(const bf16* Ahi, const bf16* Alo, const bf16* Bhi, const bf16* Blo,
             bf16* __restrict__ C)
{
  const int z = blockIdx.z;
  const size_t off = (size_t)z * DIM * DIM;
  f32x4 acc[4][4] = {};
  for (int t = 0; t < 3; ++t) {        // hi*hi + hi*lo + lo*hi
    const bf16* A  = ((t == 2) ? Alo : Ahi) + off + (size_t)blockIdx.x*128*DIM;
    const bf16* Bt = ((t == 1) ? Blo : Bhi) + off + (size_t)blockIdx.y*128*DIM;
    gemm_tile<false>(A, DIM, Bt, DIM, DIM, acc, nullptr);
  }
  const int tid = threadIdx.x, wave = tid >> 6, lane = tid & 63;
  const int wm = wave >> 1, wn = wave & 1;
  const int row0 = blockIdx.x*128 + wm*64;
  const int col0 = blockIdx.y*128 + wn*64;
#pragma unroll
  for (int ni = 0; ni < 4; ++ni) {
    const int col = col0 + ni*16 + (lane & 15);
#pragma unroll
    for (int mi = 0; mi < 4; ++mi) {
      const int row = row0 + mi*16 + (lane >> 4)*4;
#pragma unroll
      for (int r = 0; r < 4; ++r)
        C[off + (size_t)(row + r)*DIM + col] = (bf16)acc[mi][ni][r];
    }
  }
}

// w[h][d] = sum_e Wk[h][e][d] * bq[h][e]   (fp32)
__global__ __launch_bounds__(256)
void k_wvec(const float* __restrict__ Wk, const float* __restrict__ bq,
            float* __restrict__ w)
{
  const int idx = blockIdx.x*256 + threadIdx.x;   // h*512 + d
  const int d = idx & 511, h = idx >> 9;
  float s = 0.f;
  for (int e = 0; e < DIM; ++e)
    s += Wk[((size_t)(h*DIM + e))*DIM + d] * bq[h*DIM + e];
  w[idx] = s;
}

// c[h][token] = k[token] . w[h]   (fp32; wave per token, all 8 heads)
__global__ __launch_bounds__(256)
void k_cvec(const float* __restrict__ k, const float* __restrict__ w,
            float* __restrict__ c)
{
  __shared__ float ws[HEADS][DIM];
  for (int i = threadIdx.x; i < HEADS*DIM; i += 256)
    ws[i >> 9][i & 511] = w[i];
  __syncthreads();
  const int token = blockIdx.x*4 + (threadIdx.x >> 6);
  const int lane  = threadIdx.x & 63;
  const float4* kr = (const float4*)(k + (size_t)token * DIM);
  float kk[8];
  *(float4*)(kk)     = kr[lane*2];
  *(float4*)(kk + 4) = kr[lane*2 + 1];
#pragma unroll
  for (int h = 0; h < HEADS; ++h) {
    float s = 0.f;
#pragma unroll
    for (int j = 0; j < 8; ++j) s += kk[j] * ws[h][lane*8 + j];
#pragma unroll
    for (int o = 32; o >= 1; o >>= 1) s += __shfl_xor(s, o, 64);
    if (lane == 0) c[(size_t)h*BN + token] = s;
  }
}

// bc[o] = bo[o] + sum_f Wo[o][f] * bv[f&7][f>>3]   (wave per output o)
__global__ __launch_bounds__(256)
void k_bconst(const float* __restrict__ Wo, const float* __restrict__ bv,
              const float* __restrict__ bo, float* __restrict__ bc)
{
  const int o    = blockIdx.x*4 + (threadIdx.x >> 6);
  const int lane = threadIdx.x & 63;
  const float4* row = (const float4*)(Wo + ((size_t)o << 12));
  float s = 0.f;
  for (int it = 0; it < 16; ++it) {
    const int f0 = (it*64 + lane)*4;
    const float4 x = row[it*64 + lane];
    s += x.x * bv[((f0+0)&7)*DIM + ((f0+0)>>3)];
    s += x.y * bv[((f0+1)&7)*DIM + ((f0+1)>>3)];
    s += x.z * bv[((f0+2)&7)*DIM + ((f0+2)>>3)];
    s += x.w * bv[((f0+3)&7)*DIM + ((f0+3)>>3)];
  }
#pragma unroll
  for (int of = 32; of >= 1; of >>= 1) s += __shfl_xor(s, of, 64);
  if (lane == 0) bc[o] = s + bo[o];
}

// --------------------------------------------------------------- main GEMMs

// qm[z][m][c] = X[m] . MT[z][c]  (bf16 out, no bias). rows/head = gridDim.x*128
__global__ __launch_bounds__(256)
void k_qm(const bf16* __restrict__ X, const bf16* __restrict__ MT,
          bf16* __restrict__ C)
{
  const int z = blockIdx.z;
  const bf16* A  = X  + (size_t)blockIdx.x*128*DIM;
  const bf16* Bt = MT + (size_t)z*DIM*DIM + (size_t)blockIdx.y*128*DIM;
  f32x4 acc[4][4] = {};
  gemm_tile<false>(A, DIM, Bt, DIM, DIM, acc, nullptr);

  const int tid = threadIdx.x, wave = tid >> 6, lane = tid & 63;
  const int wm = wave >> 1, wn = wave & 1;
  const int rows = gridDim.x * 128;
  const int row0 = blockIdx.x*128 + wm*64;
  const int col0 = blockIdx.y*128 + wn*64;
  bf16* Cz = C + (size_t)z * rows * DIM;
#pragma unroll
  for (int ni = 0; ni < 4; ++ni) {
    const int col = col0 + ni*16 + (lane & 15);
#pragma unroll
    for (int mi = 0; mi < 4; ++mi) {
      const int row = row0 + mi*16 + (lane >> 4)*4;
#pragma unroll
      for (int r = 0; r < 4; ++r)
        Cz[(size_t)(row + r)*DIM + col] = (bf16)acc[mi][ni][r];
    }
  }
}

// vcT[(z*Bc+bloc)][o][n] = (X[m] . G[z][o]) transposed store (per-batch)
__global__ __launch_bounds__(256)
void k_vct(const bf16* __restrict__ X, const bf16* __restrict__ G,
           bf16* __restrict__ vcT, int Bc)
{
  const int z = blockIdx.z;
  const bf16* A  = X + (size_t)blockIdx.x*128*DIM;
  const bf16* Bt = G + (size_t)z*DIM*DIM + (size_t)blockIdx.y*128*DIM;
  f32x4 acc[4][4] = {};
  gemm_tile<false>(A, DIM, Bt, DIM, DIM, acc, nullptr);

  const int tid = threadIdx.x, wave = tid >> 6, lane = tid & 63;
  const int wm = wave >> 1, wn = wave & 1;
  const int gm0 = blockIdx.x * 128;
  const int bloc = gm0 >> 10;                 // SEQ = 1024
  const int n00 = (gm0 & (SEQ-1)) + wm*64;
  const int col0 = blockIdx.y*128 + wn*64;
  bf16* base = vcT + (size_t)(z*Bc + bloc) * DIM * SEQ;
#pragma unroll
  for (int ni = 0; ni < 4; ++ni) {
    const int o = col0 + ni*16 + (lane & 15);
#pragma unroll
    for (int mi = 0; mi < 4; ++mi) {
      const int n = n00 + mi*16 + (lane >> 4)*4;
      bf16x4 v;
      v[0] = (bf16)acc[mi][ni][0];
      v[1] = (bf16)acc[mi][ni][1];
      v[2] = (bf16)acc[mi][ni][2];
      v[3] = (bf16)acc[mi][ni][3];
      *(bf16x4*)(base + (size_t)o*SEQ + n) = v;
    }
  }
}

// P[z][i][j] = exp((qm_i . k_j + c_j) * scale)   (max-free softmax numerator;
// row-constant terms dropped -- they cancel in the rowsum normalization)
__global__ __launch_bounds__(256)
void k_scores(const bf16* __restrict__ QM, const bf16* __restrict__ Kb,
              const float* __restrict__ cvec, bf16* __restrict__ P,
              int Bc, int b0)
{
  const int z = blockIdx.z;
  const int h = z / Bc, bloc = z % Bc;
  const bf16* A  = QM + ((size_t)(h*Bc + bloc)*SEQ + blockIdx.x*128)*DIM;
  const bf16* Bt = Kb + ((size_t)(b0 + bloc)*SEQ + blockIdx.y*128)*DIM;
  f32x4 acc[4][4] = {};
  gemm_tile<false>(A, DIM, Bt, DIM, DIM, acc, nullptr);

  const int tid = threadIdx.x, wave = tid >> 6, lane = tid & 63;
  const int wm = wave >> 1, wn = wave & 1;
  const int row0 = blockIdx.x*128 + wm*64;
  const int col0 = blockIdx.y*128 + wn*64;
  const float* cz = cvec + (size_t)h*BN + (size_t)(b0 + bloc)*SEQ;
  bf16* Pz = P + (size_t)(h*Bc + bloc)*SEQ*SEQ;
#pragma unroll
  for (int ni = 0; ni < 4; ++ni) {
    const int col = col0 + ni*16 + (lane & 15);
    const float cc = cz[col];
#pragma unroll
    for (int mi = 0; mi < 4; ++mi) {
      const int row = row0 + mi*16 + (lane >> 4)*4;
#pragma unroll
      for (int r = 0; r < 4; ++r)
        Pz[(size_t)(row + r)*SEQ + col] = (bf16)__expf((acc[mi][ni][r] + cc) * QK_SCALE);
    }
  }
}

// rep[token][o] = sum_h (P_h[i] . vc_h[o]) / rowsum_h(i)  + bconst[o]
__global__ __launch_bounds__(256, 2)
void k_pvfinal(const bf16* __restrict__ P, const bf16* __restrict__ vcT,
               const float* __restrict__ bcon, float* __restrict__ rep,
               int Bc, int b0)
{
  const int bloc = blockIdx.z;
  f32x4 accO[4][4] = {};
  for (int h = 0; h < HEADS; ++h) {
    const bf16* A  = P   + ((size_t)(h*Bc + bloc)*SEQ + blockIdx.x*128)*SEQ;
    const bf16* Bt = vcT + ((size_t)(h*Bc + bloc)*DIM + blockIdx.y*128)*SEQ;
    f32x4 acc[4][4] = {};
    f32x4 rs[4] = {};
    gemm_tile<true>(A, SEQ, Bt, SEQ, SEQ, acc, rs);
#pragma unroll
    for (int mi = 0; mi < 4; ++mi) {
      f32x4 inv;
#pragma unroll
      for (int r = 0; r < 4; ++r) inv[r] = 1.0f / rs[mi][r];
#pragma unroll
      for (int ni = 0; ni < 4; ++ni)
#pragma unroll
        for (int r = 0; r < 4; ++r)
          accO[mi][ni][r] += acc[mi][ni][r] * inv[r];
    }
  }
  const int tid = threadIdx.x, wave = tid >> 6, lane = tid & 63;
  const int wm = wave >> 1, wn = wave & 1;
  const int row0 = (b0 + bloc)*SEQ + blockIdx.x*128 + wm*64;
  const int col0 = blockIdx.y*128 + wn*64;
#pragma unroll
  for (int ni = 0; ni < 4; ++ni) {
    const int col = col0 + ni*16 + (lane & 15);
    const float bb = bcon[col];
#pragma unroll
    for (int mi = 0; mi < 4; ++mi) {
      const int row = row0 + mi*16 + (lane >> 4)*4;
#pragma unroll
      for (int r = 0; r < 4; ++r)
        rep[(size_t)(row + r)*DIM + col] = accO[mi][ni][r] + bb;
    }
  }
}

// ------------------------------------------------------------------- launch

extern "C" void kernel_launch(void* const* d_in, const int* in_sizes, int n_in,
                              void* d_out, int out_size, void* d_ws, size_t ws_size,
                              hipStream_t stream)
{
  (void)in_sizes; (void)n_in; (void)out_size;
  const float* k_in = (const float*)d_in[0];
  const float* v_in = (const float*)d_in[1];
  const float* q_in = (const float*)d_in[2];
  const float* Wk   = (const float*)d_in[3];
  const float* bq_f = (const float*)d_in[8];
  const float* Wv   = (const float*)d_in[5];
  const float* bv_f = (const float*)d_in[6];
  const float* Wq   = (const float*)d_in[7];
  const float* Wo   = (const float*)d_in[9];
  const float* bo   = (const float*)d_in[10];

  // batch-chunk size Bc: per-chunk buffers cost Bc*32 MiB; fixed ~93 MiB
  const size_t WMAT = (size_t)HEADS*DIM*DIM*2;     // 4 MiB bf16 weight block
  const size_t fixedB = (size_t)3*BN*DIM*2 + 8*WMAT + 2*WMAT
                      + (size_t)HEADS*DIM*4 + (size_t)HEADS*BN*4 + DIM*4;
  int Bc = 1;
  for (int c : {16, 8, 4, 2, 1}) {
    const size_t need = fixedB + (size_t)c * (2*(size_t)HEADS*SEQ*DIM*2
                                              + (size_t)HEADS*SEQ*SEQ*2);
    if (need <= ws_size) { Bc = c; break; }
  }

  char* p = (char*)d_ws;
  auto take = [&](size_t bytes) { char* r = p; p += bytes; return r; };
  bf16* qbf   = (bf16*)take((size_t)BN*DIM*2);
  bf16* vbf   = (bf16*)take((size_t)BN*DIM*2);
  bf16* kbf   = (bf16*)take((size_t)BN*DIM*2);
  bf16* WqThi = (bf16*)take(WMAT);
  bf16* WqTlo = (bf16*)take(WMAT);
  bf16* WkThi = (bf16*)take(WMAT);
  bf16* WkTlo = (bf16*)take(WMAT);
  bf16* WvThi = (bf16*)take(WMAT);
  bf16* WvTlo = (bf16*)take(WMAT);
  bf16* Worhi = (bf16*)take(WMAT);
  bf16* Worlo = (bf16*)take(WMAT);
  bf16* MT    = (bf16*)take(WMAT);
  bf16* Gwv   = (bf16*)take(WMAT);
  float* wv   = (float*)take((size_t)HEADS*DIM*4);
  float* cvec = (float*)take((size_t)HEADS*BN*4);
  float* bcon = (float*)take((size_t)DIM*4);
  bf16* qm    = (bf16*)take((size_t)Bc*HEADS*SEQ*DIM*2);
  bf16* vcT   = (bf16*)take((size_t)Bc*HEADS*SEQ*DIM*2);
  bf16* Pb    = (bf16*)take((size_t)Bc*HEADS*SEQ*SEQ*2);

  const int n8x = BN*DIM/8;             // 1,048,576
  const int nW  = HEADS*DIM*DIM;        // 2,097,152
  k_cast<<<n8x/256, 256, 0, stream>>>(q_in, qbf, n8x);
  k_cast<<<n8x/256, 256, 0, stream>>>(v_in, vbf, n8x);
  k_cast<<<n8x/256, 256, 0, stream>>>(k_in, kbf, n8x);
  k_trans_hilo<<<nW/256, 256, 0, stream>>>(Wq, WqThi, WqTlo);
  k_trans_hilo<<<nW/256, 256, 0, stream>>>(Wk, WkThi, WkTlo);
  k_trans_hilo<<<nW/256, 256, 0, stream>>>(Wv, WvThi, WvTlo);
  k_wor_hilo<<<nW/256, 256, 0, stream>>>(Wo, Worhi, Worlo);
  // MT[d2][d1] = sum_e WkT[d2][e]*WqT[d1][e]  (== M[d1][d2], Bt for qm GEMM)
  k_gemm3<<<dim3(4,4,HEADS), 256, 0, stream>>>(WkThi, WkTlo, WqThi, WqTlo, MT);
  // G[o][d] = sum_e Wor[o][e]*WvT[d][e]       (Bt for vc GEMM)
  k_gemm3<<<dim3(4,4,HEADS), 256, 0, stream>>>(Worhi, Worlo, WvThi, WvTlo, Gwv);
  k_wvec<<<HEADS*DIM/256, 256, 0, stream>>>(Wk, bq_f, wv);
  k_cvec<<<BN/4, 256, 0, stream>>>(k_in, wv, cvec);
  k_bconst<<<DIM/4, 256, 0, stream>>>(Wo, bv_f, bo, bcon);

  for (int b0 = 0; b0 < BATCH; b0 += Bc) {
    dim3 gq(Bc*SEQ/128, DIM/128, HEADS);
    k_qm <<<gq, 256, 0, stream>>>(qbf + (size_t)b0*SEQ*DIM, MT, qm);
    k_vct<<<gq, 256, 0, stream>>>(vbf + (size_t)b0*SEQ*DIM, Gwv, vcT, Bc);
    dim3 gs(SEQ/128, SEQ/128, HEADS*Bc);
    k_scores<<<gs, 256, 0, stream>>>(qm, kbf, cvec, Pb, Bc, b0);
    dim3 gv(SEQ/128, DIM/128, Bc);
    k_pvfinal<<<gv, 256, 0, stream>>>(Pb, vcT, bcon, (float*)d_out, Bc, b0);
  }
}

// Round 5
// 1333.276 us; speedup vs baseline: 1.0813x; 1.0813x over previous
//
#include <hip/hip_runtime.h>

typedef __bf16 bf16;
typedef __bf16 bf16x8 __attribute__((ext_vector_type(8)));
typedef __bf16 bf16x4 __attribute__((ext_vector_type(4)));
typedef float  f32x4  __attribute__((ext_vector_type(4)));

#define BATCH 16
#define SEQ   1024
#define DIM   512
#define HEADS 8
#define BN    (BATCH*SEQ)
#define QK_SCALE 0.04419417382415922f  /* 1/sqrt(512) */

// ---------------------------------------------------------------- utilities

__device__ __forceinline__ void load16_lds(const void* g, void* l) {
  // async global->LDS, 16B per lane; LDS dest = wave-uniform base + lane*16
  __builtin_amdgcn_global_load_lds((__attribute__((address_space(1))) void*)g,
                                   (__attribute__((address_space(3))) void*)l,
                                   16, 0, 0);
}

// ---------------------------------------------------------------- GEMM core
// C_tile(128x128) += A_tile(128xK) * B_tile(128xK)^T, bf16 in, fp32 acc.
// 2-phase prefetch double-buffer; single __syncthreads per K-step.
// LDS layout is FRAG-ORDERED: staging lane l holds global (row=l&15,
// k8=(l>>4)) of its 16-row chunk, so LDS element (r,k) sits at
// ((k>>3)*16+r)*16B and the MFMA fragment read is chunk_base + lane*16B --
// perfectly linear, zero bank conflicts (fix for 4-8 way conflicts of the
// row-major [16][32] layout).  RS: also accumulate row-sums of A via
// ones-vector MFMA.
template<bool RS>
__device__ __forceinline__ void gemm_tile(const bf16* __restrict__ Atile, int lda,
                                          const bf16* __restrict__ Btile, int ldb,
                                          int K, f32x4 acc[4][4], f32x4 rs[4])
{
  __shared__ bf16 As[2][128*32];
  __shared__ bf16 Bs[2][128*32];
  const int tid  = threadIdx.x;
  const int wave = tid >> 6;
  const int lane = tid & 63;
  const int wm = wave >> 1, wn = wave & 1;
  const int srow = lane & 15;          // staging: row within 16-row chunk
  const int scol = (lane >> 4) * 8;    // staging: k-offset (8 bf16 = 16B)

  bf16x8 ones;
#pragma unroll
  for (int j = 0; j < 8; ++j) ones[j] = (bf16)1.0f;

  __syncthreads();                     // protect LDS reuse (callers loop)
#pragma unroll
  for (int i = 0; i < 2; ++i) {        // prologue: stage tile 0 -> buf 0
    const int c = wave * 2 + i;
    load16_lds(Atile + (size_t)(c*16 + srow) * lda + scol, &As[0][c*512]);
    load16_lds(Btile + (size_t)(c*16 + srow) * ldb + scol, &Bs[0][c*512]);
  }
  __syncthreads();                     // vmcnt(0) drained: buf 0 ready

  int cur = 0;
  for (int kt = 0; kt < K; kt += 32) {
    const int nxt = kt + 32;
    if (nxt < K) {                     // prefetch next tile into buf cur^1
#pragma unroll
      for (int i = 0; i < 2; ++i) {
        const int c = wave * 2 + i;
        load16_lds(Atile + (size_t)(c*16 + srow) * lda + nxt + scol, &As[cur^1][c*512]);
        load16_lds(Btile + (size_t)(c*16 + srow) * ldb + nxt + scol, &Bs[cur^1][c*512]);
      }
    }
    bf16x8 af[4], bfr[4];
#pragma unroll
    for (int mi = 0; mi < 4; ++mi)     // frag-ordered: linear lane*16B read
      af[mi] = *(const bf16x8*)(&As[cur][(wm*4 + mi)*512 + lane*8]);
#pragma unroll
    for (int ni = 0; ni < 4; ++ni)
      bfr[ni] = *(const bf16x8*)(&Bs[cur][(wn*4 + ni)*512 + lane*8]);
#pragma unroll
    for (int mi = 0; mi < 4; ++mi) {
#pragma unroll
      for (int ni = 0; ni < 4; ++ni)
        acc[mi][ni] = __builtin_amdgcn_mfma_f32_16x16x32_bf16(af[mi], bfr[ni],
                                                              acc[mi][ni], 0, 0, 0);
      if (RS)
        rs[mi] = __builtin_amdgcn_mfma_f32_16x16x32_bf16(af[mi], ones, rs[mi], 0, 0, 0);
    }
    __syncthreads();                   // drains prefetch vmcnt; all reads done
    cur ^= 1;
  }
}

// C/D fragment mapping (m89-verified): col = lane&15, row = (lane>>4)*4 + r.

// ----------------------------------------------------- weight-prep kernels

// fp32 -> bf16 cast, 8 elems/thread
__global__ __launch_bounds__(256)
void k_cast(const float* __restrict__ in, bf16* __restrict__ out, int n8)
{
  const int i = blockIdx.x*256 + threadIdx.x;
  if (i >= n8) return;
  const float4* p = (const float4*)in + (size_t)i*2;
  const float4 a = p[0], b = p[1];
  bf16x8 o;
  o[0]=(bf16)a.x; o[1]=(bf16)a.y; o[2]=(bf16)a.z; o[3]=(bf16)a.w;
  o[4]=(bf16)b.x; o[5]=(bf16)b.y; o[6]=(bf16)b.z; o[7]=(bf16)b.w;
  *((bf16x8*)out + i) = o;
}

// T[h][d][e] = W[h][e][d], split into hi/lo bf16 (lo = v - (float)hi)
__global__ __launch_bounds__(256)
void k_trans_hilo(const float* __restrict__ W, bf16* __restrict__ Thi,
                  bf16* __restrict__ Tlo)
{
  const int idx = blockIdx.x*256 + threadIdx.x;   // h*2^18 + d*2^9 + e
  const int e = idx & 511, d = (idx >> 9) & 511, h = idx >> 18;
  const float v = W[((size_t)(h*DIM + e))*DIM + d];
  const bf16 hi = (bf16)v;
  Thi[idx] = hi;
  Tlo[idx] = (bf16)(v - (float)hi);
}

// Wor[h][o][e] = Wo[o][e*8+h], hi/lo split
__global__ __launch_bounds__(256)
void k_wor_hilo(const float* __restrict__ Wo, bf16* __restrict__ Whi,
                bf16* __restrict__ Wlo)
{
  const int idx = blockIdx.x*256 + threadIdx.x;   // h*2^18 + o*2^9 + e
  const int e = idx & 511, o = (idx >> 9) & 511, h = idx >> 18;
  const float v = Wo[((size_t)o << 12) + (e << 3) + h];
  const bf16 hi = (bf16)v;
  Whi[idx] = hi;
  Wlo[idx] = (bf16)(v - (float)hi);
}

// C[z][m][n] = sum_k A[z][m][k]*B[z][n][k] with hi/lo split (3 cross terms),
// bf16 output.  Used for MT = WkT x WqT  and  G = Wor x WvT.
__global__ __launch_bounds__(256)
void k_gemm3(const bf16* Ahi, const bf16* Alo, const bf16* Bhi, const bf16* Blo,
             bf16* __restrict__ C)
{
  const int z = blockIdx.z;
  const size_t off = (size_t)z * DIM * DIM;
  f32x4 acc[4][4] = {};
  for (int t = 0; t < 3; ++t) {        // hi*hi + hi*lo + lo*hi
    const bf16* A  = ((t == 2) ? Alo : Ahi) + off + (size_t)blockIdx.x*128*DIM;
    const bf16* Bt = ((t == 1) ? Blo : Bhi) + off + (size_t)blockIdx.y*128*DIM;
    gemm_tile<false>(A, DIM, Bt, DIM, DIM, acc, nullptr);
  }
  const int tid = threadIdx.x, wave = tid >> 6, lane = tid & 63;
  const int wm = wave >> 1, wn = wave & 1;
  const int row0 = blockIdx.x*128 + wm*64;
  const int col0 = blockIdx.y*128 + wn*64;
#pragma unroll
  for (int ni = 0; ni < 4; ++ni) {
    const int col = col0 + ni*16 + (lane & 15);
#pragma unroll
    for (int mi = 0; mi < 4; ++mi) {
      const int row = row0 + mi*16 + (lane >> 4)*4;
#pragma unroll
      for (int r = 0; r < 4; ++r)
        C[off + (size_t)(row + r)*DIM + col] = (bf16)acc[mi][ni][r];
    }
  }
}

// w[h][d] = sum_e Wk[h][e][d] * bq[h][e]   (fp32)
__global__ __launch_bounds__(256)
void k_wvec(const float* __restrict__ Wk, const float* __restrict__ bq,
            float* __restrict__ w)
{
  const int idx = blockIdx.x*256 + threadIdx.x;   // h*512 + d
  const int d = idx & 511, h = idx >> 9;
  float s = 0.f;
  for (int e = 0; e < DIM; ++e)
    s += Wk[((size_t)(h*DIM + e))*DIM + d] * bq[h*DIM + e];
  w[idx] = s;
}

// c[h][token] = k[token] . w[h]   (fp32; wave per token, all 8 heads)
__global__ __launch_bounds__(256)
void k_cvec(const float* __restrict__ k, const float* __restrict__ w,
            float* __restrict__ c)
{
  __shared__ float ws[HEADS][DIM];
  for (int i = threadIdx.x; i < HEADS*DIM; i += 256)
    ws[i >> 9][i & 511] = w[i];
  __syncthreads();
  const int token = blockIdx.x*4 + (threadIdx.x >> 6);
  const int lane  = threadIdx.x & 63;
  const float4* kr = (const float4*)(k + (size_t)token * DIM);
  float kk[8];
  *(float4*)(kk)     = kr[lane*2];
  *(float4*)(kk + 4) = kr[lane*2 + 1];
#pragma unroll
  for (int h = 0; h < HEADS; ++h) {
    float s = 0.f;
#pragma unroll
    for (int j = 0; j < 8; ++j) s += kk[j] * ws[h][lane*8 + j];
#pragma unroll
    for (int o = 32; o >= 1; o >>= 1) s += __shfl_xor(s, o, 64);
    if (lane == 0) c[(size_t)h*BN + token] = s;
  }
}

// bc[o] = bo[o] + sum_f Wo[o][f] * bv[f&7][f>>3]   (wave per output o)
__global__ __launch_bounds__(256)
void k_bconst(const float* __restrict__ Wo, const float* __restrict__ bv,
              const float* __restrict__ bo, float* __restrict__ bc)
{
  const int o    = blockIdx.x*4 + (threadIdx.x >> 6);
  const int lane = threadIdx.x & 63;
  const float4* row = (const float4*)(Wo + ((size_t)o << 12));
  float s = 0.f;
  for (int it = 0; it < 16; ++it) {
    const int f0 = (it*64 + lane)*4;
    const float4 x = row[it*64 + lane];
    s += x.x * bv[((f0+0)&7)*DIM + ((f0+0)>>3)];
    s += x.y * bv[((f0+1)&7)*DIM + ((f0+1)>>3)];
    s += x.z * bv[((f0+2)&7)*DIM + ((f0+2)>>3)];
    s += x.w * bv[((f0+3)&7)*DIM + ((f0+3)>>3)];
  }
#pragma unroll
  for (int of = 32; of >= 1; of >>= 1) s += __shfl_xor(s, of, 64);
  if (lane == 0) bc[o] = s + bo[o];
}

// --------------------------------------------------------------- main GEMMs

// qm[z][m][c] = X[m] . MT[z][c]  (bf16 out, no bias). rows/head = gridDim.x*128
__global__ __launch_bounds__(256)
void k_qm(const bf16* __restrict__ X, const bf16* __restrict__ MT,
          bf16* __restrict__ C)
{
  const int z = blockIdx.z;
  const bf16* A  = X  + (size_t)blockIdx.x*128*DIM;
  const bf16* Bt = MT + (size_t)z*DIM*DIM + (size_t)blockIdx.y*128*DIM;
  f32x4 acc[4][4] = {};
  gemm_tile<false>(A, DIM, Bt, DIM, DIM, acc, nullptr);

  const int tid = threadIdx.x, wave = tid >> 6, lane = tid & 63;
  const int wm = wave >> 1, wn = wave & 1;
  const int rows = gridDim.x * 128;
  const int row0 = blockIdx.x*128 + wm*64;
  const int col0 = blockIdx.y*128 + wn*64;
  bf16* Cz = C + (size_t)z * rows * DIM;
#pragma unroll
  for (int ni = 0; ni < 4; ++ni) {
    const int col = col0 + ni*16 + (lane & 15);
#pragma unroll
    for (int mi = 0; mi < 4; ++mi) {
      const int row = row0 + mi*16 + (lane >> 4)*4;
#pragma unroll
      for (int r = 0; r < 4; ++r)
        Cz[(size_t)(row + r)*DIM + col] = (bf16)acc[mi][ni][r];
    }
  }
}

// vcT[(z*Bc+bloc)][o][n] = (X[m] . G[z][o]) transposed store (per-batch)
__global__ __launch_bounds__(256)
void k_vct(const bf16* __restrict__ X, const bf16* __restrict__ G,
           bf16* __restrict__ vcT, int Bc)
{
  const int z = blockIdx.z;
  const bf16* A  = X + (size_t)blockIdx.x*128*DIM;
  const bf16* Bt = G + (size_t)z*DIM*DIM + (size_t)blockIdx.y*128*DIM;
  f32x4 acc[4][4] = {};
  gemm_tile<false>(A, DIM, Bt, DIM, DIM, acc, nullptr);

  const int tid = threadIdx.x, wave = tid >> 6, lane = tid & 63;
  const int wm = wave >> 1, wn = wave & 1;
  const int gm0 = blockIdx.x * 128;
  const int bloc = gm0 >> 10;                 // SEQ = 1024
  const int n00 = (gm0 & (SEQ-1)) + wm*64;
  const int col0 = blockIdx.y*128 + wn*64;
  bf16* base = vcT + (size_t)(z*Bc + bloc) * DIM * SEQ;
#pragma unroll
  for (int ni = 0; ni < 4; ++ni) {
    const int o = col0 + ni*16 + (lane & 15);
#pragma unroll
    for (int mi = 0; mi < 4; ++mi) {
      const int n = n00 + mi*16 + (lane >> 4)*4;
      bf16x4 v;
      v[0] = (bf16)acc[mi][ni][0];
      v[1] = (bf16)acc[mi][ni][1];
      v[2] = (bf16)acc[mi][ni][2];
      v[3] = (bf16)acc[mi][ni][3];
      *(bf16x4*)(base + (size_t)o*SEQ + n) = v;
    }
  }
}

// P[z][i][j] = exp((qm_i . k_j + c_j) * scale)   (max-free softmax numerator;
// row-constant terms dropped -- they cancel in the rowsum normalization)
__global__ __launch_bounds__(256)
void k_scores(const bf16* __restrict__ QM, const bf16* __restrict__ Kb,
              const float* __restrict__ cvec, bf16* __restrict__ P,
              int Bc, int b0)
{
  const int z = blockIdx.z;
  const int h = z / Bc, bloc = z % Bc;
  const bf16* A  = QM + ((size_t)(h*Bc + bloc)*SEQ + blockIdx.x*128)*DIM;
  const bf16* Bt = Kb + ((size_t)(b0 + bloc)*SEQ + blockIdx.y*128)*DIM;
  f32x4 acc[4][4] = {};
  gemm_tile<false>(A, DIM, Bt, DIM, DIM, acc, nullptr);

  const int tid = threadIdx.x, wave = tid >> 6, lane = tid & 63;
  const int wm = wave >> 1, wn = wave & 1;
  const int row0 = blockIdx.x*128 + wm*64;
  const int col0 = blockIdx.y*128 + wn*64;
  const float* cz = cvec + (size_t)h*BN + (size_t)(b0 + bloc)*SEQ;
  bf16* Pz = P + (size_t)(h*Bc + bloc)*SEQ*SEQ;
#pragma unroll
  for (int ni = 0; ni < 4; ++ni) {
    const int col = col0 + ni*16 + (lane & 15);
    const float cc = cz[col];
#pragma unroll
    for (int mi = 0; mi < 4; ++mi) {
      const int row = row0 + mi*16 + (lane >> 4)*4;
#pragma unroll
      for (int r = 0; r < 4; ++r)
        Pz[(size_t)(row + r)*SEQ + col] = (bf16)__expf((acc[mi][ni][r] + cc) * QK_SCALE);
    }
  }
}

// outh[z][i][o] = (P_z[i] . vc_z[o]) / rowsum_z(i)     z = h*Bc + bloc
__global__ __launch_bounds__(256)
void k_pv(const bf16* __restrict__ P, const bf16* __restrict__ vcT,
          bf16* __restrict__ outh)
{
  const int z = blockIdx.z;
  const bf16* A  = P   + ((size_t)z*SEQ + blockIdx.x*128)*SEQ;
  const bf16* Bt = vcT + ((size_t)z*DIM + blockIdx.y*128)*SEQ;
  f32x4 acc[4][4] = {};
  f32x4 rs[4] = {};
  gemm_tile<true>(A, SEQ, Bt, SEQ, SEQ, acc, rs);

  const int tid = threadIdx.x, wave = tid >> 6, lane = tid & 63;
  const int wm = wave >> 1, wn = wave & 1;
  const int row0 = blockIdx.x*128 + wm*64;
  const int col0 = blockIdx.y*128 + wn*64;
  bf16* Oz = outh + (size_t)z * SEQ * DIM;
  f32x4 inv[4];
#pragma unroll
  for (int mi = 0; mi < 4; ++mi)
#pragma unroll
    for (int r = 0; r < 4; ++r)
      inv[mi][r] = 1.0f / rs[mi][r];
#pragma unroll
  for (int ni = 0; ni < 4; ++ni) {
    const int col = col0 + ni*16 + (lane & 15);
#pragma unroll
    for (int mi = 0; mi < 4; ++mi) {
      const int row = row0 + mi*16 + (lane >> 4)*4;
#pragma unroll
      for (int r = 0; r < 4; ++r)
        Oz[(size_t)(row + r)*DIM + col] = (bf16)(acc[mi][ni][r] * inv[mi][r]);
    }
  }
}

// rep[(b0+bloc)*SEQ + n][o] = sum_h outh[(h*Bc+bloc)][n][o] + bcon[o]
__global__ __launch_bounds__(256)
void k_hsum(const bf16* __restrict__ outh, const float* __restrict__ bcon,
            float* __restrict__ rep, int Bc, int b0)
{
  const int bloc = blockIdx.z;
  const int i = blockIdx.x*256 + threadIdx.x;   // 8-elem group in SEQ*DIM
  const int o0 = (i & 63) * 8;
  const int n  = i >> 6;
  float s[8];
  *(float4*)(s)     = *(const float4*)(bcon + o0);
  *(float4*)(s + 4) = *(const float4*)(bcon + o0 + 4);
#pragma unroll
  for (int h = 0; h < HEADS; ++h) {
    const bf16x8 v = *(const bf16x8*)(outh + ((size_t)(h*Bc + bloc)*SEQ + n)*DIM + o0);
#pragma unroll
    for (int j = 0; j < 8; ++j) s[j] += (float)v[j];
  }
  float* dst = rep + ((size_t)(b0 + bloc)*SEQ + n)*DIM + o0;
  *(float4*)(dst)     = *(const float4*)(s);
  *(float4*)(dst + 4) = *(const float4*)(s + 4);
}

// ------------------------------------------------------------------- launch

extern "C" void kernel_launch(void* const* d_in, const int* in_sizes, int n_in,
                              void* d_out, int out_size, void* d_ws, size_t ws_size,
                              hipStream_t stream)
{
  (void)in_sizes; (void)n_in; (void)out_size;
  const float* k_in = (const float*)d_in[0];
  const float* v_in = (const float*)d_in[1];
  const float* q_in = (const float*)d_in[2];
  const float* Wk   = (const float*)d_in[3];
  const float* bq_f = (const float*)d_in[8];
  const float* Wv   = (const float*)d_in[5];
  const float* bv_f = (const float*)d_in[6];
  const float* Wq   = (const float*)d_in[7];
  const float* Wo   = (const float*)d_in[9];
  const float* bo   = (const float*)d_in[10];

  // batch-chunk size Bc: per-chunk buffers (qm, vcT, P, outh)
  const size_t WMAT = (size_t)HEADS*DIM*DIM*2;     // 4 MiB bf16 weight block
  const size_t fixedB = (size_t)3*BN*DIM*2 + 10*WMAT
                      + (size_t)HEADS*DIM*4 + (size_t)HEADS*BN*4 + DIM*4;
  const size_t perBc = (size_t)3*HEADS*SEQ*DIM*2 + (size_t)HEADS*SEQ*SEQ*2;
  int Bc = 1;
  for (int c : {16, 8, 4, 2, 1}) {
    if (fixedB + (size_t)c * perBc <= ws_size) { Bc = c; break; }
  }

  char* p = (char*)d_ws;
  auto take = [&](size_t bytes) { char* r = p; p += bytes; return r; };
  bf16* qbf   = (bf16*)take((size_t)BN*DIM*2);
  bf16* vbf   = (bf16*)take((size_t)BN*DIM*2);
  bf16* kbf   = (bf16*)take((size_t)BN*DIM*2);
  bf16* WqThi = (bf16*)take(WMAT);
  bf16* WqTlo = (bf16*)take(WMAT);
  bf16* WkThi = (bf16*)take(WMAT);
  bf16* WkTlo = (bf16*)take(WMAT);
  bf16* WvThi = (bf16*)take(WMAT);
  bf16* WvTlo = (bf16*)take(WMAT);
  bf16* Worhi = (bf16*)take(WMAT);
  bf16* Worlo = (bf16*)take(WMAT);
  bf16* MT    = (bf16*)take(WMAT);
  bf16* Gwv   = (bf16*)take(WMAT);
  float* wv   = (float*)take((size_t)HEADS*DIM*4);
  float* cvec = (float*)take((size_t)HEADS*BN*4);
  float* bcon = (float*)take((size_t)DIM*4);
  bf16* qm    = (bf16*)take((size_t)Bc*HEADS*SEQ*DIM*2);
  bf16* vcT   = (bf16*)take((size_t)Bc*HEADS*SEQ*DIM*2);
  bf16* outh  = (bf16*)take((size_t)Bc*HEADS*SEQ*DIM*2);
  bf16* Pb    = (bf16*)take((size_t)Bc*HEADS*SEQ*SEQ*2);

  const int n8x = BN*DIM/8;             // 1,048,576
  const int nW  = HEADS*DIM*DIM;        // 2,097,152
  k_cast<<<n8x/256, 256, 0, stream>>>(q_in, qbf, n8x);
  k_cast<<<n8x/256, 256, 0, stream>>>(v_in, vbf, n8x);
  k_cast<<<n8x/256, 256, 0, stream>>>(k_in, kbf, n8x);
  k_trans_hilo<<<nW/256, 256, 0, stream>>>(Wq, WqThi, WqTlo);
  k_trans_hilo<<<nW/256, 256, 0, stream>>>(Wk, WkThi, WkTlo);
  k_trans_hilo<<<nW/256, 256, 0, stream>>>(Wv, WvThi, WvTlo);
  k_wor_hilo<<<nW/256, 256, 0, stream>>>(Wo, Worhi, Worlo);
  // MT[d2][d1] = sum_e WkT[d2][e]*WqT[d1][e]  (== M[d1][d2], Bt for qm GEMM)
  k_gemm3<<<dim3(4,4,HEADS), 256, 0, stream>>>(WkThi, WkTlo, WqThi, WqTlo, MT);
  // G[o][d] = sum_e Wor[o][e]*WvT[d][e]       (Bt for vc GEMM)
  k_gemm3<<<dim3(4,4,HEADS), 256, 0, stream>>>(Worhi, Worlo, WvThi, WvTlo, Gwv);
  k_wvec<<<HEADS*DIM/256, 256, 0, stream>>>(Wk, bq_f, wv);
  k_cvec<<<BN/4, 256, 0, stream>>>(k_in, wv, cvec);
  k_bconst<<<DIM/4, 256, 0, stream>>>(Wo, bv_f, bo, bcon);

  for (int b0 = 0; b0 < BATCH; b0 += Bc) {
    dim3 gq(Bc*SEQ/128, DIM/128, HEADS);
    k_qm <<<gq, 256, 0, stream>>>(qbf + (size_t)b0*SEQ*DIM, MT, qm);
    k_vct<<<gq, 256, 0, stream>>>(vbf + (size_t)b0*SEQ*DIM, Gwv, vcT, Bc);
    dim3 gs(SEQ/128, SEQ/128, HEADS*Bc);
    k_scores<<<gs, 256, 0, stream>>>(qm, kbf, cvec, Pb, Bc, b0);
    dim3 gv(SEQ/128, DIM/128, HEADS*Bc);
    k_pv<<<gv, 256, 0, stream>>>(Pb, vcT, outh);
    dim3 gh(SEQ*DIM/8/256, 1, Bc);
    k_hsum<<<gh, 256, 0, stream>>>(outh, bcon, (float*)d_out, Bc, b0);
  }
}

// Round 7
// 1056.828 us; speedup vs baseline: 1.3642x; 1.2616x over previous
//
#include <hip/hip_runtime.h>

typedef __bf16 bf16;
typedef __bf16 bf16x8 __attribute__((ext_vector_type(8)));
typedef __bf16 bf16x4 __attribute__((ext_vector_type(4)));
typedef float  f32x4  __attribute__((ext_vector_type(4)));

#define BATCH 16
#define SEQ   1024
#define DIM   512
#define HEADS 8
#define BN    (BATCH*SEQ)
#define QK_SCALE 0.04419417382415922f  /* 1/sqrt(512) */

// ---------------------------------------------------------------- utilities

__device__ __forceinline__ void load16_lds(const void* g, void* l) {
  // async global->LDS, 16B per lane; LDS dest = wave-uniform base + lane*16
  __builtin_amdgcn_global_load_lds((__attribute__((address_space(1))) void*)g,
                                   (__attribute__((address_space(3))) void*)l,
                                   16, 0, 0);
}

// ================================================================ 256x256 core
// 8 waves (2M x 4N), BK=64, double-buffered (2 K-tiles in LDS, 2 in flight),
// counted vmcnt(8) -- never drained to 0 in the main loop (T3+T4), raw
// s_barrier, setprio around MFMA clusters (T5).
// LDS is FRAG-ORDERED (HW-validated 0-conflict in round 5): segment
// s = chunk*2 + ksub occupies bytes [s*1024, s*1024+1024); lane l holds
// (row = chunk*16 + (l&15), k = ksub*32 + (l>>4)*8 ..+8).  MFMA fragment
// read = segment_base + lane*16B, perfectly linear.  global_load_lds dest
// stays linear (rule #21): the permutation lives in the per-lane GLOBAL
// source address.

__device__ __forceinline__ void g256_stage(const bf16* __restrict__ A, int lda,
                                           const bf16* __restrict__ B, int ldb,
                                           int kt, bf16* dA, bf16* dB,
                                           int wave, int lane)
{
  const int r16 = lane & 15, k8 = (lane >> 4) * 8;
#pragma unroll
  for (int i = 0; i < 4; ++i) {
    const int s   = i*8 + wave;          // 32 segments of 1 KiB
    const int row = (s >> 1)*16 + r16;
    const int kk  = kt + (s & 1)*32 + k8;
    load16_lds(A + (size_t)row*lda + kk, (char*)dA + s*1024);
    load16_lds(B + (size_t)row*ldb + kk, (char*)dB + s*1024);
  }
}

__device__ __forceinline__ void g256_core(const bf16* __restrict__ A, int lda,
                                          const bf16* __restrict__ B, int ldb,
                                          int K, f32x4 acc[8][4],
                                          bf16 (*sA)[16384], bf16 (*sB)[16384])
{
  const int tid = threadIdx.x, wave = tid >> 6, lane = tid & 63;
  const int wm = wave >> 2, wn = wave & 3;   // 2 x 4 wave grid

  // prologue: stage tiles 0,1; wait tile 0 (8 oldest of 16)
  g256_stage(A, lda, B, ldb, 0,  sA[0], sB[0], wave, lane);
  g256_stage(A, lda, B, ldb, 64, sA[1], sB[1], wave, lane);
  asm volatile("s_waitcnt vmcnt(8)" ::: "memory");
  __builtin_amdgcn_s_barrier();
  __builtin_amdgcn_sched_barrier(0);

  const int NT = K >> 6;
  for (int t = 0; t < NT; ++t) {
    const int cur = t & 1;
    const bf16* lA = sA[cur];
    const bf16* lB = sB[cur];

    // ---- ks = 0: frags + MFMA
    bf16x8 af0[8], bf0[4];
#pragma unroll
    for (int mi = 0; mi < 8; ++mi)
      af0[mi] = *(const bf16x8*)(lA + ((wm*8 + mi)*2 + 0)*512 + lane*8);
#pragma unroll
    for (int ni = 0; ni < 4; ++ni)
      bf0[ni] = *(const bf16x8*)(lB + ((wn*4 + ni)*2 + 0)*512 + lane*8);
    __builtin_amdgcn_s_setprio(1);
#pragma unroll
    for (int mi = 0; mi < 8; ++mi)
#pragma unroll
      for (int ni = 0; ni < 4; ++ni)
        acc[mi][ni] = __builtin_amdgcn_mfma_f32_16x16x32_bf16(af0[mi], bf0[ni],
                                                              acc[mi][ni], 0, 0, 0);
    __builtin_amdgcn_s_setprio(0);

    // ---- ks = 1: frags into regs, then release buf[cur] for restage
    bf16x8 af1[8], bf1[4];
#pragma unroll
    for (int mi = 0; mi < 8; ++mi)
      af1[mi] = *(const bf16x8*)(lA + ((wm*8 + mi)*2 + 1)*512 + lane*8);
#pragma unroll
    for (int ni = 0; ni < 4; ++ni)
      bf1[ni] = *(const bf16x8*)(lB + ((wn*4 + ni)*2 + 1)*512 + lane*8);
    asm volatile("s_waitcnt lgkmcnt(0)" ::: "memory");   // my reads of buf[cur] done
    __builtin_amdgcn_sched_barrier(0);
    __builtin_amdgcn_s_barrier();                        // ALL waves done reading
    __builtin_amdgcn_sched_barrier(0);

    if (t + 2 < NT)                                      // restage consumed buffer
      g256_stage(A, lda, B, ldb, (t + 2)*64, sA[cur], sB[cur], wave, lane);

    __builtin_amdgcn_s_setprio(1);
#pragma unroll
    for (int mi = 0; mi < 8; ++mi)
#pragma unroll
      for (int ni = 0; ni < 4; ++ni)
        acc[mi][ni] = __builtin_amdgcn_mfma_f32_16x16x32_bf16(af1[mi], bf1[ni],
                                                              acc[mi][ni], 0, 0, 0);
    __builtin_amdgcn_s_setprio(0);

    // tile t+1 must be landed before next iter reads buf[cur^1]
    if (t + 2 < NT) asm volatile("s_waitcnt vmcnt(8)" ::: "memory");
    else            asm volatile("s_waitcnt vmcnt(0)" ::: "memory");
    __builtin_amdgcn_s_barrier();
    __builtin_amdgcn_sched_barrier(0);
  }
}

// C/D fragment mapping (m89-verified): col = lane&15, row = (lane>>4)*4 + r.

// --------------------------------------------------------------- main GEMMs

// qm[z][m][c] = X[m] . MT[z][c]
__global__ __launch_bounds__(512, 2)
void g256_qm(const bf16* __restrict__ X, const bf16* __restrict__ MT,
             bf16* __restrict__ C)
{
  __shared__ bf16 sA[2][16384], sB[2][16384];
  const int z = blockIdx.z;
  const bf16* A  = X  + (size_t)blockIdx.x*256*DIM;
  const bf16* Bt = MT + (size_t)z*DIM*DIM + (size_t)blockIdx.y*256*DIM;
  f32x4 acc[8][4] = {};
  g256_core(A, DIM, Bt, DIM, DIM, acc, sA, sB);

  const int tid = threadIdx.x, wave = tid >> 6, lane = tid & 63;
  const int wm = wave >> 2, wn = wave & 3;
  const int rows = gridDim.x * 256;
  bf16* Cz = C + (size_t)z * rows * DIM;
  const int row0 = blockIdx.x*256 + wm*128;
  const int col0 = blockIdx.y*256 + wn*64;
#pragma unroll
  for (int ni = 0; ni < 4; ++ni) {
    const int col = col0 + ni*16 + (lane & 15);
#pragma unroll
    for (int mi = 0; mi < 8; ++mi) {
      const int row = row0 + mi*16 + (lane >> 4)*4;
#pragma unroll
      for (int r = 0; r < 4; ++r)
        Cz[(size_t)(row + r)*DIM + col] = (bf16)acc[mi][ni][r];
    }
  }
}

// vcT[(z*Bc+bloc)][o][n] = X[m] . G[z][o], transposed store per batch
__global__ __launch_bounds__(512, 2)
void g256_vct(const bf16* __restrict__ X, const bf16* __restrict__ G,
              bf16* __restrict__ vcT, int Bc)
{
  __shared__ bf16 sA[2][16384], sB[2][16384];
  const int z = blockIdx.z;
  const bf16* A  = X + (size_t)blockIdx.x*256*DIM;
  const bf16* Bt = G + (size_t)z*DIM*DIM + (size_t)blockIdx.y*256*DIM;
  f32x4 acc[8][4] = {};
  g256_core(A, DIM, Bt, DIM, DIM, acc, sA, sB);

  const int tid = threadIdx.x, wave = tid >> 6, lane = tid & 63;
  const int wm = wave >> 2, wn = wave & 3;
  const int gm0  = blockIdx.x * 256;
  const int bloc = gm0 >> 10;                  // SEQ = 1024
  const int n00  = (gm0 & (SEQ-1)) + wm*128;
  const int col0 = blockIdx.y*256 + wn*64;
  bf16* base = vcT + (size_t)(z*Bc + bloc) * DIM * SEQ;
#pragma unroll
  for (int ni = 0; ni < 4; ++ni) {
    const int o = col0 + ni*16 + (lane & 15);
#pragma unroll
    for (int mi = 0; mi < 8; ++mi) {
      const int n = n00 + mi*16 + (lane >> 4)*4;
      bf16x4 v;
      v[0] = (bf16)acc[mi][ni][0];
      v[1] = (bf16)acc[mi][ni][1];
      v[2] = (bf16)acc[mi][ni][2];
      v[3] = (bf16)acc[mi][ni][3];
      *(bf16x4*)(base + (size_t)o*SEQ + n) = v;
    }
  }
}

// P[z][i][j] = exp((qm_i.k_j + c_j)*scale); also emits per-64col row partial
// sums rpart[z][p][i] (p = blockIdx.y*4 + wn, 16 parts) -- deterministic,
// no atomics; k_pv sums the 16 parts.
__global__ __launch_bounds__(512, 2)
void g256_scores(const bf16* __restrict__ QM, const bf16* __restrict__ Kb,
                 const float* __restrict__ cvec, bf16* __restrict__ P,
                 float* __restrict__ rpart, int Bc, int b0)
{
  __shared__ bf16 sA[2][16384], sB[2][16384];
  const int z = blockIdx.z;
  const int h = z / Bc, bloc = z % Bc;
  const bf16* A  = QM + ((size_t)(h*Bc + bloc)*SEQ + blockIdx.x*256)*DIM;
  const bf16* Bt = Kb + ((size_t)(b0 + bloc)*SEQ + blockIdx.y*256)*DIM;
  f32x4 acc[8][4] = {};
  g256_core(A, DIM, Bt, DIM, DIM, acc, sA, sB);

  const int tid = threadIdx.x, wave = tid >> 6, lane = tid & 63;
  const int wm = wave >> 2, wn = wave & 3;
  const float* cz = cvec + (size_t)h*BN + (size_t)(b0 + bloc)*SEQ + blockIdx.y*256;
  bf16* Pz = P + (size_t)(h*Bc + bloc)*SEQ*SEQ;
  float cc[4];
#pragma unroll
  for (int ni = 0; ni < 4; ++ni) cc[ni] = cz[wn*64 + ni*16 + (lane & 15)];
  float* rp = rpart + ((size_t)(h*Bc + bloc)*16 + blockIdx.y*4 + wn)*SEQ
            + blockIdx.x*256;
#pragma unroll
  for (int mi = 0; mi < 8; ++mi) {
#pragma unroll
    for (int r = 0; r < 4; ++r) {
      const int row = wm*128 + mi*16 + (lane >> 4)*4 + r;   // tile-local
      float pv[4], s = 0.f;
#pragma unroll
      for (int ni = 0; ni < 4; ++ni) {
        pv[ni] = __expf((acc[mi][ni][r] + cc[ni]) * QK_SCALE);
        s += pv[ni];
      }
#pragma unroll
      for (int ni = 0; ni < 4; ++ni)
        Pz[(size_t)(blockIdx.x*256 + row)*SEQ
           + blockIdx.y*256 + wn*64 + ni*16 + (lane & 15)] = (bf16)pv[ni];
      s += __shfl_xor(s, 1, 16); s += __shfl_xor(s, 2, 16);
      s += __shfl_xor(s, 4, 16); s += __shfl_xor(s, 8, 16);
      if ((lane & 15) == 0) rp[row] = s;
    }
  }
}

// outh[z][i][o] = (P_z[i] . vc_z[o]) / rowsum_z(i)
__global__ __launch_bounds__(512, 2)
void g256_pv(const bf16* __restrict__ P, const bf16* __restrict__ vcT,
             const float* __restrict__ rpart, bf16* __restrict__ outh)
{
  __shared__ bf16 sA[2][16384], sB[2][16384];
  __shared__ float rinv[256];
  const int z = blockIdx.z;
  const bf16* A  = P   + ((size_t)z*SEQ + blockIdx.x*256)*SEQ;
  const bf16* Bt = vcT + ((size_t)z*DIM + blockIdx.y*256)*SEQ;
  f32x4 acc[8][4] = {};
  g256_core(A, SEQ, Bt, SEQ, SEQ, acc, sA, sB);

  const int tid = threadIdx.x, wave = tid >> 6, lane = tid & 63;
  const int wm = wave >> 2, wn = wave & 3;
  if (tid < 256) {
    const float* rp = rpart + (size_t)z*16*SEQ + blockIdx.x*256 + tid;
    float s = 0.f;
#pragma unroll
    for (int p = 0; p < 16; ++p) s += rp[p*SEQ];
    rinv[tid] = 1.0f / s;
  }
  __syncthreads();
  bf16* Oz = outh + (size_t)z * SEQ * DIM;
  const int row0 = blockIdx.x*256 + wm*128;
  const int col0 = blockIdx.y*256 + wn*64;
#pragma unroll
  for (int ni = 0; ni < 4; ++ni) {
    const int col = col0 + ni*16 + (lane & 15);
#pragma unroll
    for (int mi = 0; mi < 8; ++mi) {
      const int lr = wm*128 + mi*16 + (lane >> 4)*4;
#pragma unroll
      for (int r = 0; r < 4; ++r)
        Oz[(size_t)(row0 + mi*16 + (lane >> 4)*4 + r)*DIM + col] =
            (bf16)(acc[mi][ni][r] * rinv[lr + r]);
    }
  }
}

// ======================================================== 128x128 prep core
// (round-5 validated, 0 bank conflicts) -- used only for tiny weight GEMMs.
__device__ __forceinline__ void gemm_tile(const bf16* __restrict__ Atile, int lda,
                                          const bf16* __restrict__ Btile, int ldb,
                                          int K, f32x4 acc[4][4])
{
  __shared__ bf16 As[2][128*32];
  __shared__ bf16 Bs[2][128*32];
  const int tid  = threadIdx.x;
  const int wave = tid >> 6;
  const int lane = tid & 63;
  const int wm = wave >> 1, wn = wave & 1;
  const int srow = lane & 15;
  const int scol = (lane >> 4) * 8;

  __syncthreads();
#pragma unroll
  for (int i = 0; i < 2; ++i) {
    const int c = wave * 2 + i;
    load16_lds(Atile + (size_t)(c*16 + srow) * lda + scol, &As[0][c*512]);
    load16_lds(Btile + (size_t)(c*16 + srow) * ldb + scol, &Bs[0][c*512]);
  }
  __syncthreads();

  int cur = 0;
  for (int kt = 0; kt < K; kt += 32) {
    const int nxt = kt + 32;
    if (nxt < K) {
#pragma unroll
      for (int i = 0; i < 2; ++i) {
        const int c = wave * 2 + i;
        load16_lds(Atile + (size_t)(c*16 + srow) * lda + nxt + scol, &As[cur^1][c*512]);
        load16_lds(Btile + (size_t)(c*16 + srow) * ldb + nxt + scol, &Bs[cur^1][c*512]);
      }
    }
    bf16x8 af[4], bfr[4];
#pragma unroll
    for (int mi = 0; mi < 4; ++mi)
      af[mi] = *(const bf16x8*)(&As[cur][(wm*4 + mi)*512 + lane*8]);
#pragma unroll
    for (int ni = 0; ni < 4; ++ni)
      bfr[ni] = *(const bf16x8*)(&Bs[cur][(wn*4 + ni)*512 + lane*8]);
#pragma unroll
    for (int mi = 0; mi < 4; ++mi)
#pragma unroll
      for (int ni = 0; ni < 4; ++ni)
        acc[mi][ni] = __builtin_amdgcn_mfma_f32_16x16x32_bf16(af[mi], bfr[ni],
                                                              acc[mi][ni], 0, 0, 0);
    __syncthreads();
    cur ^= 1;
  }
}

// ----------------------------------------------------- weight-prep kernels

__global__ __launch_bounds__(256)
void k_cast(const float* __restrict__ in, bf16* __restrict__ out, int n8)
{
  const int i = blockIdx.x*256 + threadIdx.x;
  if (i >= n8) return;
  const float4* p = (const float4*)in + (size_t)i*2;
  const float4 a = p[0], b = p[1];
  bf16x8 o;
  o[0]=(bf16)a.x; o[1]=(bf16)a.y; o[2]=(bf16)a.z; o[3]=(bf16)a.w;
  o[4]=(bf16)b.x; o[5]=(bf16)b.y; o[6]=(bf16)b.z; o[7]=(bf16)b.w;
  *((bf16x8*)out + i) = o;
}

__global__ __launch_bounds__(256)
void k_trans_hilo(const float* __restrict__ W, bf16* __restrict__ Thi,
                  bf16* __restrict__ Tlo)
{
  const int idx = blockIdx.x*256 + threadIdx.x;   // h*2^18 + d*2^9 + e
  const int e = idx & 511, d = (idx >> 9) & 511, h = idx >> 18;
  const float v = W[((size_t)(h*DIM + e))*DIM + d];
  const bf16 hi = (bf16)v;
  Thi[idx] = hi;
  Tlo[idx] = (bf16)(v - (float)hi);
}

__global__ __launch_bounds__(256)
void k_wor_hilo(const float* __restrict__ Wo, bf16* __restrict__ Whi,
                bf16* __restrict__ Wlo)
{
  const int idx = blockIdx.x*256 + threadIdx.x;   // h*2^18 + o*2^9 + e
  const int e = idx & 511, o = (idx >> 9) & 511, h = idx >> 18;
  const float v = Wo[((size_t)o << 12) + (e << 3) + h];
  const bf16 hi = (bf16)v;
  Whi[idx] = hi;
  Wlo[idx] = (bf16)(v - (float)hi);
}

__global__ __launch_bounds__(256)
void k_gemm3(const bf16* Ahi, const bf16* Alo, const bf16* Bhi, const bf16* Blo,
             bf16* __restrict__ C)
{
  const int z = blockIdx.z;
  const size_t off = (size_t)z * DIM * DIM;
  f32x4 acc[4][4] = {};
  for (int t = 0; t < 3; ++t) {        // hi*hi + hi*lo + lo*hi
    const bf16* A  = ((t == 2) ? Alo : Ahi) + off + (size_t)blockIdx.x*128*DIM;
    const bf16* Bt = ((t == 1) ? Blo : Bhi) + off + (size_t)blockIdx.y*128*DIM;
    gemm_tile(A, DIM, Bt, DIM, DIM, acc);
  }
  const int tid = threadIdx.x, wave = tid >> 6, lane = tid & 63;
  const int wm = wave >> 1, wn = wave & 1;
  const int row0 = blockIdx.x*128 + wm*64;
  const int col0 = blockIdx.y*128 + wn*64;
#pragma unroll
  for (int ni = 0; ni < 4; ++ni) {
    const int col = col0 + ni*16 + (lane & 15);
#pragma unroll
    for (int mi = 0; mi < 4; ++mi) {
      const int row = row0 + mi*16 + (lane >> 4)*4;
#pragma unroll
      for (int r = 0; r < 4; ++r)
        C[off + (size_t)(row + r)*DIM + col] = (bf16)acc[mi][ni][r];
    }
  }
}

__global__ __launch_bounds__(256)
void k_wvec(const float* __restrict__ Wk, const float* __restrict__ bq,
            float* __restrict__ w)
{
  const int idx = blockIdx.x*256 + threadIdx.x;   // h*512 + d
  const int d = idx & 511, h = idx >> 9;
  float s = 0.f;
  for (int e = 0; e < DIM; ++e)
    s += Wk[((size_t)(h*DIM + e))*DIM + d] * bq[h*DIM + e];
  w[idx] = s;
}

__global__ __launch_bounds__(256)
void k_cvec(const float* __restrict__ k, const float* __restrict__ w,
            float* __restrict__ c)
{
  __shared__ float ws[HEADS][DIM];
  for (int i = threadIdx.x; i < HEADS*DIM; i += 256)
    ws[i >> 9][i & 511] = w[i];
  __syncthreads();
  const int token = blockIdx.x*4 + (threadIdx.x >> 6);
  const int lane  = threadIdx.x & 63;
  const float4* kr = (const float4*)(k + (size_t)token * DIM);
  float kk[8];
  *(float4*)(kk)     = kr[lane*2];
  *(float4*)(kk + 4) = kr[lane*2 + 1];
#pragma unroll
  for (int h = 0; h < HEADS; ++h) {
    float s = 0.f;
#pragma unroll
    for (int j = 0; j < 8; ++j) s += kk[j] * ws[h][lane*8 + j];
#pragma unroll
    for (int o = 32; o >= 1; o >>= 1) s += __shfl_xor(s, o, 64);
    if (lane == 0) c[(size_t)h*BN + token] = s;
  }
}

__global__ __launch_bounds__(256)
void k_bconst(const float* __restrict__ Wo, const float* __restrict__ bv,
              const float* __restrict__ bo, float* __restrict__ bc)
{
  const int o    = blockIdx.x*4 + (threadIdx.x >> 6);
  const int lane = threadIdx.x & 63;
  const float4* row = (const float4*)(Wo + ((size_t)o << 12));
  float s = 0.f;
  for (int it = 0; it < 16; ++it) {
    const int f0 = (it*64 + lane)*4;
    const float4 x = row[it*64 + lane];
    s += x.x * bv[((f0+0)&7)*DIM + ((f0+0)>>3)];
    s += x.y * bv[((f0+1)&7)*DIM + ((f0+1)>>3)];
    s += x.z * bv[((f0+2)&7)*DIM + ((f0+2)>>3)];
    s += x.w * bv[((f0+3)&7)*DIM + ((f0+3)>>3)];
  }
#pragma unroll
  for (int of = 32; of >= 1; of >>= 1) s += __shfl_xor(s, of, 64);
  if (lane == 0) bc[o] = s + bo[o];
}

// rep[(b0+bloc)*SEQ + n][o] = sum_h outh[(h*Bc+bloc)][n][o] + bcon[o]
__global__ __launch_bounds__(256)
void k_hsum(const bf16* __restrict__ outh, const float* __restrict__ bcon,
            float* __restrict__ rep, int Bc, int b0)
{
  const int bloc = blockIdx.z;
  const int i = blockIdx.x*256 + threadIdx.x;   // 8-elem group in SEQ*DIM
  const int o0 = (i & 63) * 8;
  const int n  = i >> 6;
  float s[8];
  *(float4*)(s)     = *(const float4*)(bcon + o0);
  *(float4*)(s + 4) = *(const float4*)(bcon + o0 + 4);
#pragma unroll
  for (int h = 0; h < HEADS; ++h) {
    const bf16x8 v = *(const bf16x8*)(outh + ((size_t)(h*Bc + bloc)*SEQ + n)*DIM + o0);
#pragma unroll
    for (int j = 0; j < 8; ++j) s[j] += (float)v[j];
  }
  float* dst = rep + ((size_t)(b0 + bloc)*SEQ + n)*DIM + o0;
  *(float4*)(dst)     = *(const float4*)(s);
  *(float4*)(dst + 4) = *(const float4*)(s + 4);
}

// ------------------------------------------------------------------- launch

extern "C" void kernel_launch(void* const* d_in, const int* in_sizes, int n_in,
                              void* d_out, int out_size, void* d_ws, size_t ws_size,
                              hipStream_t stream)
{
  (void)in_sizes; (void)n_in; (void)out_size;
  const float* k_in = (const float*)d_in[0];
  const float* v_in = (const float*)d_in[1];
  const float* q_in = (const float*)d_in[2];
  const float* Wk   = (const float*)d_in[3];
  const float* bq_f = (const float*)d_in[8];
  const float* Wv   = (const float*)d_in[5];
  const float* bv_f = (const float*)d_in[6];
  const float* Wq   = (const float*)d_in[7];
  const float* Wo   = (const float*)d_in[9];
  const float* bo   = (const float*)d_in[10];

  const size_t WMAT = (size_t)HEADS*DIM*DIM*2;     // 4 MiB bf16 weight block
  const size_t fixedB = (size_t)3*BN*DIM*2 + 10*WMAT
                      + (size_t)HEADS*DIM*4 + (size_t)HEADS*BN*4 + DIM*4;
  const size_t perBc = (size_t)3*HEADS*SEQ*DIM*2 + (size_t)HEADS*SEQ*SEQ*2
                     + (size_t)HEADS*16*SEQ*4;
  int Bc = 1;
  for (int c : {16, 8, 4, 2, 1}) {
    if (fixedB + (size_t)c * perBc <= ws_size) { Bc = c; break; }
  }

  char* p = (char*)d_ws;
  auto take = [&](size_t bytes) { char* r = p; p += bytes; return r; };
  bf16* qbf   = (bf16*)take((size_t)BN*DIM*2);
  bf16* vbf   = (bf16*)take((size_t)BN*DIM*2);
  bf16* kbf   = (bf16*)take((size_t)BN*DIM*2);
  bf16* WqThi = (bf16*)take(WMAT);
  bf16* WqTlo = (bf16*)take(WMAT);
  bf16* WkThi = (bf16*)take(WMAT);
  bf16* WkTlo = (bf16*)take(WMAT);
  bf16* WvThi = (bf16*)take(WMAT);
  bf16* WvTlo = (bf16*)take(WMAT);
  bf16* Worhi = (bf16*)take(WMAT);
  bf16* Worlo = (bf16*)take(WMAT);
  bf16* MT    = (bf16*)take(WMAT);
  bf16* Gwv   = (bf16*)take(WMAT);
  float* wv   = (float*)take((size_t)HEADS*DIM*4);
  float* cvec = (float*)take((size_t)HEADS*BN*4);
  float* bcon = (float*)take((size_t)DIM*4);
  bf16* qm    = (bf16*)take((size_t)Bc*HEADS*SEQ*DIM*2);
  bf16* vcT   = (bf16*)take((size_t)Bc*HEADS*SEQ*DIM*2);
  bf16* outh  = (bf16*)take((size_t)Bc*HEADS*SEQ*DIM*2);
  bf16* Pb    = (bf16*)take((size_t)Bc*HEADS*SEQ*SEQ*2);
  float* rpart= (float*)take((size_t)Bc*HEADS*16*SEQ*4);

  const int n8x = BN*DIM/8;             // 1,048,576
  const int nW  = HEADS*DIM*DIM;        // 2,097,152
  k_cast<<<n8x/256, 256, 0, stream>>>(q_in, qbf, n8x);
  k_cast<<<n8x/256, 256, 0, stream>>>(v_in, vbf, n8x);
  k_cast<<<n8x/256, 256, 0, stream>>>(k_in, kbf, n8x);
  k_trans_hilo<<<nW/256, 256, 0, stream>>>(Wq, WqThi, WqTlo);
  k_trans_hilo<<<nW/256, 256, 0, stream>>>(Wk, WkThi, WkTlo);
  k_trans_hilo<<<nW/256, 256, 0, stream>>>(Wv, WvThi, WvTlo);
  k_wor_hilo<<<nW/256, 256, 0, stream>>>(Wo, Worhi, Worlo);
  k_gemm3<<<dim3(4,4,HEADS), 256, 0, stream>>>(WkThi, WkTlo, WqThi, WqTlo, MT);
  k_gemm3<<<dim3(4,4,HEADS), 256, 0, stream>>>(Worhi, Worlo, WvThi, WvTlo, Gwv);
  k_wvec<<<HEADS*DIM/256, 256, 0, stream>>>(Wk, bq_f, wv);
  k_cvec<<<BN/4, 256, 0, stream>>>(k_in, wv, cvec);
  k_bconst<<<DIM/4, 256, 0, stream>>>(Wo, bv_f, bo, bcon);

  for (int b0 = 0; b0 < BATCH; b0 += Bc) {
    dim3 gq(Bc*SEQ/256, DIM/256, HEADS);
    g256_qm <<<gq, 512, 0, stream>>>(qbf + (size_t)b0*SEQ*DIM, MT, qm);
    g256_vct<<<gq, 512, 0, stream>>>(vbf + (size_t)b0*SEQ*DIM, Gwv, vcT, Bc);
    dim3 gs(SEQ/256, SEQ/256, HEADS*Bc);
    g256_scores<<<gs, 512, 0, stream>>>(qm, kbf, cvec, Pb, rpart, Bc, b0);
    dim3 gv(SEQ/256, DIM/256, HEADS*Bc);
    g256_pv<<<gv, 512, 0, stream>>>(Pb, vcT, rpart, outh);
    dim3 gh(SEQ*DIM/8/256, 1, Bc);
    k_hsum<<<gh, 256, 0, stream>>>(outh, bcon, (float*)d_out, Bc, b0);
  }
}